// Round 8
// baseline (343.072 us; speedup 1.0000x reference)
//
#include <hip/hip_runtime.h>
#include <hip/hip_bf16.h>
#include <hip/hip_fp16.h>

#define NUM_RAYS 4096
#define S_PER 96
#define NPTS (NUM_RAYS * S_PER)
#define CCH 80
#define HID 64

// ws layout (byte offsets)
#define WSB_W2     256       // 256 f32 (64x4)
#define WSB_B1     1536      // 64 f32
#define WSB_B2     1856      // 4 f32
#define WSB_W1S    4096      // 15360 f16 shorts, compact MFMA B-frag order (30720 B)
#define WSB_PT     40960     // 983040 f16: planesT [p][y*64+x][80]  (1.97 MB)

// w1s compact layout (shorts): plane p base = p*5120;
//  ccl 0,1: + ccl*2048 + (nb*64+lane)*8 + j        (k = 8*quad+j, ch = ccl*32+k)
//  ccl 2:   + 4096     + (nb*32+(lane&31))*8 + j   (quads 0,1 only; ch = 64+8*quad+j)
//
// R17 (global B-frags) REGRESSED 232->316: vmcnt before every MFMA + 2x L2.
// R19 (pipeline + launch_bounds(256,4)) REGRESSED: the 64-VGPR cap spilled
//   2.7GB to scratch. CONFOUNDED — pipeline itself untested until now.
// R20 WIN 232->203: f16 feature path, packed v_pk_fma_f16 bilinear.
// R21 NEUTRAL: LDS 32768 lifted the LDS cap to 5 blocks/CU but occupancy/dur
//   flat — occupancy is VGPR-BINNED (waves halve at 64/128/256, m69): at
//   VGPR 80 we sit in the (64,128] bin = 4 waves/SIMD no matter what LDS is.
//   => VGPR 80..128 is FREE headroom. Occupancy path closed.
// R23: spend free VGPRs on the R18 1-step tap-prefetch pipeline (9 flat
//   (plane,ccl) steps, dbuf 8x uint4, NO launch_bounds cap); w2s back to
//   LDS (frees 16 VGPR; LDS irrelevant); DPP rotate-reduce (row_ror 1/2/4/8
//   v_add_f32) replaces 28 ds_swizzle shfl_xor + lgkmcnt waits.

// d_out layout (elements of output dtype):
// [0) comp_rgb 3*4096 | [12288) depth 4096 | [16384) opacity 4096
// [20480) comp_normal 3*4096 | [32768) sdf_grad 393216*3

typedef __attribute__((ext_vector_type(8))) _Float16 half8;
typedef __attribute__((ext_vector_type(4))) float f32x4;

__device__ __forceinline__ float bf2f(__hip_bfloat16 v) { return __bfloat162float(v); }

// f32 -> f16 bits (RTN)
__device__ __forceinline__ short f2hs(float f) {
  __half h = __float2half(f);
  short s; __builtin_memcpy(&s, &h, 2); return s;
}

template <bool BF16>
__device__ __forceinline__ float ldin(const void* p, size_t i) {
  if (BF16) return bf2f(((const __hip_bfloat16*)p)[i]);
  else      return ((const float*)p)[i];
}
template <bool BF16>
__device__ __forceinline__ void stout(void* p, size_t i, float v) {
  if (BF16) ((__hip_bfloat16*)p)[i] = __float2bfloat16(v);
  else      ((float*)p)[i] = v;
}

__device__ __forceinline__ __half2 h2cast(unsigned u) {
  __half2 r; __builtin_memcpy(&r, &u, 4); return r;
}

// DPP rotate-add: v += row_ror<N>(v). Pure VALU (no DS op, no lgkmcnt).
// Rotate-reduce over rotations 1,2,4,8 sums all 16 lanes of each DPP row.
#define DPP_ADD(V, CTRL)                                                     \
  do {                                                                       \
    int s_ = __float_as_int(V);                                              \
    int t_ = __builtin_amdgcn_update_dpp(0, s_, (CTRL), 0xF, 0xF, true);     \
    V += __int_as_float(t_);                                                 \
  } while (0)

// Per-wave dtype self-detection: bf16 ray-dir norms ~1; f32-misread is garbage.
__device__ __forceinline__ bool detect_bf16(const void* rdv) {
  int lane = threadIdx.x & 63;
  const __hip_bfloat16* p = (const __hip_bfloat16*)rdv;
  float x = bf2f(p[lane * 3 + 0]);
  float y = bf2f(p[lane * 3 + 1]);
  float z = bf2f(p[lane * 3 + 2]);
  float n2 = x * x + y * y + z * z;
  bool ok = (n2 > 0.95f) && (n2 < 1.05f);
  return __ballot(ok) == ~0ull;
}

template <bool BF16>
__device__ __forceinline__ void prep_body(const void* __restrict__ W1,
                                          const void* __restrict__ b1,
                                          const void* __restrict__ W2,
                                          const void* __restrict__ b2,
                                          float* __restrict__ ws, int tid) {
  unsigned short* w1sw = (unsigned short*)((char*)ws + WSB_W1S);
  if (tid < 15360) {
    int p = tid / 5120;
    int r = tid - p * 5120;
    int ch, n;
    if (r < 4096) {
      int ccl  = r >> 11;
      int r2   = r & 2047;
      int j    = r2 & 7;
      int lane = (r2 >> 3) & 63;
      int nb   = r2 >> 9;
      ch = ccl * 32 + 8 * (lane >> 4) + j;
      n  = nb * 16 + (lane & 15);
    } else {
      int r2   = r - 4096;
      int j    = r2 & 7;
      int l31  = (r2 >> 3) & 31;
      int nb   = r2 >> 8;
      ch = 64 + 8 * (l31 >> 4) + j;
      n  = nb * 16 + (l31 & 15);
    }
    w1sw[tid] = (unsigned short)f2hs(ldin<BF16>(W1, (size_t)(p * 80 + ch) * 64 + n));
  }
  float* w2f = (float*)((char*)ws + WSB_W2);
  float* b1f = (float*)((char*)ws + WSB_B1);
  float* b2f = (float*)((char*)ws + WSB_B2);
  if (tid < 256) w2f[tid] = ldin<BF16>(W2, tid);
  if (tid < 64)  b1f[tid] = ldin<BF16>(b1, tid);
  if (tid < 4)   b2f[tid] = ldin<BF16>(b2, tid);
}

// planes[p][c][y][x] -> planesT[p][y*64+x][80] (f16, channel-last).
template <bool BF16>
__device__ __forceinline__ void transpose_body(const void* __restrict__ planes,
                                               float* __restrict__ ws) {
  int b  = blockIdx.x;
  int tt = b & 15;
  int ct = (b >> 4) % 5;
  int p  = b / 80;
  int tex = tt * 256 + threadIdx.x;
  unsigned u[8];
  #pragma unroll
  for (int i = 0; i < 8; i++) {
    int c0 = ct * 16 + 2 * i;
    float v0 = ldin<BF16>(planes, ((size_t)(p * 80 + c0) * 4096) + tex);
    float v1 = ldin<BF16>(planes, ((size_t)(p * 80 + c0 + 1) * 4096) + tex);
    unsigned s0 = (unsigned short)f2hs(v0);
    unsigned s1 = (unsigned short)f2hs(v1);
    u[i] = s0 | (s1 << 16);
  }
  unsigned short* ptb = (unsigned short*)((char*)ws + WSB_PT);
  uint4* dst = (uint4*)(ptb + ((size_t)(p * 4096 + tex) * 80 + ct * 16));
  dst[0] = make_uint4(u[0], u[1], u[2], u[3]);
  dst[1] = make_uint4(u[4], u[5], u[6], u[7]);
}

// blocks 0..239: plane transpose; blocks 240..303: weight prep
__global__ void setup_kernel(const void* __restrict__ planes,
                             const void* __restrict__ W1,
                             const void* __restrict__ b1,
                             const void* __restrict__ W2,
                             const void* __restrict__ b2,
                             const void* __restrict__ rd,
                             float* __restrict__ ws) {
  bool bf = detect_bf16(rd);
  if (blockIdx.x < 240) {
    if (bf) transpose_body<true >(planes, ws);
    else    transpose_body<false>(planes, ws);
  } else {
    int tid = (blockIdx.x - 240) * 256 + threadIdx.x;
    if (bf) prep_body<true >(W1, b1, W2, b2, ws, tid);
    else    prep_body<false>(W1, b1, W2, b2, ws, tid);
  }
}

struct TapInfo {
  float w00, w10, w01, w11;
  int o00, o10, o01, o11;   // texel indices (y*64+x)
};
__device__ __forceinline__ TapInfo tap_setup(float u, float v) {
  TapInfo t;
  float fx = u * 32.0f + 31.5f;
  float fy = v * 32.0f + 31.5f;
  float flx = floorf(fx), fly = floorf(fy);
  int x0 = (int)flx, y0 = (int)fly;
  float wx = fx - flx, wy = fy - fly;
  int x1 = x0 + 1, y1 = y0 + 1;
  bool vx0 = (x0 >= 0) && (x0 < 64);
  bool vx1 = (x1 >= 0) && (x1 < 64);
  bool vy0 = (y0 >= 0) && (y0 < 64);
  bool vy1 = (y1 >= 0) && (y1 < 64);
  int cx0 = min(max(x0, 0), 63), cx1 = min(max(x1, 0), 63);
  int cy0 = min(max(y0, 0), 63), cy1 = min(max(y1, 0), 63);
  t.w00 = (1.0f - wx) * (1.0f - wy) * ((vx0 && vy0) ? 1.0f : 0.0f);
  t.w10 = wx * (1.0f - wy)          * ((vx1 && vy0) ? 1.0f : 0.0f);
  t.w01 = (1.0f - wx) * wy          * ((vx0 && vy1) ? 1.0f : 0.0f);
  t.w11 = wx * wy                   * ((vx1 && vy1) ? 1.0f : 0.0f);
  t.o00 = cy0 * 64 + cx0; t.o10 = cy0 * 64 + cx1;
  t.o01 = cy1 * 64 + cx0; t.o11 = cy1 * 64 + cx1;
  return t;
}

// Block = 1 ray (256 threads) — R12 shape.
// R23: flat 9-step (plane,ccl) pipeline, taps prefetched 1 step ahead.
template <bool BF16>
__device__ __forceinline__ void fused_body(const void* __restrict__ ro,
                                           const void* __restrict__ rd,
                                           const float* __restrict__ ws,
                                           void* __restrict__ out,
                                           unsigned short* __restrict__ w1s,
                                           float* __restrict__ w2s,
                                           float* __restrict__ rec_v0,
                                           __half (*__restrict__ rec_h)[6],
                                           float* __restrict__ xfer,
                                           float (*__restrict__ red)[8]) {
  const unsigned short* ptb = (const unsigned short*)((const char*)ws + WSB_PT);
  const float* w2f = (const float*)((const char*)ws + WSB_W2);
  const float* b1f = (const float*)((const char*)ws + WSB_B1);
  const float* b2f = (const float*)((const char*)ws + WSB_B2);

  int tid = threadIdx.x;
  int wave = tid >> 6;
  int lane = tid & 63;
  int lane15 = lane & 15;
  int quad = lane >> 4;
  int ray = blockIdx.x;

  // stage compact W1 (1920 uint4) + W2 into LDS
  {
    const uint4* src = (const uint4*)((const char*)ws + WSB_W1S);
    uint4* dst = (uint4*)w1s;
    #pragma unroll
    for (int t = 0; t < 8; t++) {
      int idx = tid + 256 * t;
      if (idx < 1920) dst[idx] = src[idx];
    }
  }
  w2s[tid] = w2f[tid];

  // ray data (uniform across block)
  float ox = ldin<BF16>(ro, (size_t)ray*3+0), oy = ldin<BF16>(ro, (size_t)ray*3+1), oz = ldin<BF16>(ro, (size_t)ray*3+2);
  float dx = ldin<BF16>(rd, (size_t)ray*3+0), dy = ldin<BF16>(rd, (size_t)ray*3+1), dz = ldin<BF16>(rd, (size_t)ray*3+2);
  float o3[3] = {ox, oy, oz}, d3[3] = {dx, dy, dz};
  float tmin = -1e30f, tmax = 1e30f;
  #pragma unroll
  for (int k = 0; k < 3; k++) {
    float sd = (fabsf(d3[k]) < 1e-9f) ? 1e-9f : d3[k];
    float ta = (-0.6f - o3[k]) / sd;
    float tb = ( 0.6f - o3[k]) / sd;
    tmin = fmaxf(tmin, fminf(ta, tb));
    tmax = fminf(tmax, fmaxf(ta, tb));
  }
  float tn = fmaxf(tmin, 0.0f);
  float span = fmaxf(tmax - tn, 0.0f);
  float delta = span * (1.0f / (float)S_PER);
  // per-lane b1 (4 VGPRs)
  float b1x[4];
  #pragma unroll
  for (int nb = 0; nb < 4; nb++) b1x[nb] = b1f[nb * 16 + lane15];

  __syncthreads();

  // lane's byte base into planesT (incl. its 8*quad-channel slice)
  const char* pb = (const char*)ptb + 16 * quad;

  #pragma unroll 1
  for (int it = 0; it < 6; it++) {
    int sbase = it * 16 + wave * 4;

    // ---- feature stage: lane feeds A-row m = lane15 (sample sF, decode d)
    int sF = sbase + (lane15 >> 2);
    int d  = lane15 & 3;
    float depF = tn + span * (((float)sF + 0.5f) * (1.0f / (float)S_PER));
    float px = ox + depF * dx, py = oy + depF * dy, pz = oz + depF * dz;
    if (d == 1) px += 0.01f;
    if (d == 2) py += 0.01f;
    if (d == 3) pz += 0.01f;
    if (d > 0) {
      px = fminf(fmaxf(px, -0.6f), 0.6f);
      py = fminf(fmaxf(py, -0.6f), 0.6f);
      pz = fminf(fmaxf(pz, -0.6f), 0.6f);
    }
    const float inv = 1.0f / 0.6f;
    float ux = px * inv, uy = py * inv, uz = pz * inv;

    // all 3 tap setups up front (plane 0: (x,y), 1: (x,z), 2: (y,z))
    TapInfo t0 = tap_setup(ux, uy);
    TapInfo t1 = tap_setup(ux, uz);
    TapInfo t2 = tap_setup(uy, uz);
    // byte offsets (texel*160 B + plane*655360 B), 32-bit
    unsigned f000 = (unsigned)(t0.o00 * 160);
    unsigned f010 = (unsigned)(t0.o10 * 160);
    unsigned f001 = (unsigned)(t0.o01 * 160);
    unsigned f011 = (unsigned)(t0.o11 * 160);
    unsigned f100 = (unsigned)(t1.o00 * 160) + 655360u;
    unsigned f110 = (unsigned)(t1.o10 * 160) + 655360u;
    unsigned f101 = (unsigned)(t1.o01 * 160) + 655360u;
    unsigned f111 = (unsigned)(t1.o11 * 160) + 655360u;
    unsigned f200 = (unsigned)(t2.o00 * 160) + 1310720u;
    unsigned f210 = (unsigned)(t2.o10 * 160) + 1310720u;
    unsigned f201 = (unsigned)(t2.o01 * 160) + 1310720u;
    unsigned f211 = (unsigned)(t2.o11 * 160) + 1310720u;
    // f16 broadcast weights per plane
    __half2 h000 = __float2half2_rn(t0.w00), h010 = __float2half2_rn(t0.w10);
    __half2 h001 = __float2half2_rn(t0.w01), h011 = __float2half2_rn(t0.w11);
    __half2 h100 = __float2half2_rn(t1.w00), h110 = __float2half2_rn(t1.w10);
    __half2 h101 = __float2half2_rn(t1.w01), h111 = __float2half2_rn(t1.w11);
    __half2 h200 = __float2half2_rn(t2.w00), h210 = __float2half2_rn(t2.w10);
    __half2 h201 = __float2half2_rn(t2.w01), h211 = __float2half2_rn(t2.w11);

    f32x4 acc[4];
    #pragma unroll
    for (int nb = 0; nb < 4; nb++) acc[nb] = (f32x4){0.f, 0.f, 0.f, 0.f};

    uint4 A0, A1, A2, A3, B0, B1, B2, B3;

    // issue 4 corner tap loads at byte offsets (+64B per ccl)
#define LOADT(D0, D1, D2, D3, O00, O10, O01, O11, CCL)                        \
    do {                                                                      \
      if ((CCL) < 2 || quad < 2) {                                            \
        D0 = *(const uint4*)(pb + O00 + 64 * (CCL));                          \
        D1 = *(const uint4*)(pb + O10 + 64 * (CCL));                          \
        D2 = *(const uint4*)(pb + O01 + 64 * (CCL));                          \
        D3 = *(const uint4*)(pb + O11 + 64 * (CCL));                          \
      }                                                                       \
    } while (0)

    // f16 blend S0..S3 -> A-frag; 4 MFMAs with LDS B-frags
#define BLENDT(S0, S1, S2, S3, W00, W10, W01, W11, P, CCL)                    \
    do {                                                                      \
      int4 afi = {0, 0, 0, 0};                                                \
      if ((CCL) < 2 || quad < 2) {                                            \
        unsigned u00_[4] = {S0.x, S0.y, S0.z, S0.w};                          \
        unsigned u10_[4] = {S1.x, S1.y, S1.z, S1.w};                          \
        unsigned u01_[4] = {S2.x, S2.y, S2.z, S2.w};                          \
        unsigned u11_[4] = {S3.x, S3.y, S3.z, S3.w};                          \
        int ae_[4];                                                           \
        _Pragma("unroll")                                                     \
        for (int q = 0; q < 4; q++) {                                         \
          __half2 f = __hmul2(h2cast(u00_[q]), W00);                          \
          f = __hfma2(h2cast(u10_[q]), W10, f);                               \
          f = __hfma2(h2cast(u01_[q]), W01, f);                               \
          f = __hfma2(h2cast(u11_[q]), W11, f);                               \
          int fi_; __builtin_memcpy(&fi_, &f, 4);                             \
          ae_[q] = fi_;                                                       \
        }                                                                     \
        afi.x = ae_[0]; afi.y = ae_[1]; afi.z = ae_[2]; afi.w = ae_[3];       \
      }                                                                       \
      half8 afr;                                                              \
      __builtin_memcpy(&afr, &afi, 16);                                       \
      _Pragma("unroll")                                                       \
      for (int nb = 0; nb < 4; nb++) {                                        \
        int boff = ((CCL) < 2) ? ((CCL) * 2048 + (nb * 64 + lane) * 8)        \
                               : (4096 + (nb * 32 + (lane & 31)) * 8);        \
        half8 bfr = *(const half8*)(w1s + (P) * 5120 + boff);                 \
        acc[nb] = __builtin_amdgcn_mfma_f32_16x16x32_f16(afr, bfr, acc[nb], 0, 0, 0); \
      }                                                                       \
    } while (0)

    // 9-step pipeline: loads for step s+1 issue before blend of step s
    LOADT(A0, A1, A2, A3, f000, f010, f001, f011, 0);
    LOADT(B0, B1, B2, B3, f000, f010, f001, f011, 1);  BLENDT(A0, A1, A2, A3, h000, h010, h001, h011, 0, 0);
    LOADT(A0, A1, A2, A3, f000, f010, f001, f011, 2);  BLENDT(B0, B1, B2, B3, h000, h010, h001, h011, 0, 1);
    LOADT(B0, B1, B2, B3, f100, f110, f101, f111, 0);  BLENDT(A0, A1, A2, A3, h000, h010, h001, h011, 0, 2);
    LOADT(A0, A1, A2, A3, f100, f110, f101, f111, 1);  BLENDT(B0, B1, B2, B3, h100, h110, h101, h111, 1, 0);
    LOADT(B0, B1, B2, B3, f100, f110, f101, f111, 2);  BLENDT(A0, A1, A2, A3, h100, h110, h101, h111, 1, 1);
    LOADT(A0, A1, A2, A3, f200, f210, f201, f211, 0);  BLENDT(B0, B1, B2, B3, h100, h110, h101, h111, 1, 2);
    LOADT(B0, B1, B2, B3, f200, f210, f201, f211, 1);  BLENDT(A0, A1, A2, A3, h200, h210, h201, h211, 2, 0);
    LOADT(A0, A1, A2, A3, f200, f210, f201, f211, 2);  BLENDT(B0, B1, B2, B3, h200, h210, h201, h211, 2, 1);
                                                       BLENDT(A0, A1, A2, A3, h200, h210, h201, h211, 2, 2);
#undef LOADT
#undef BLENDT

    // ---- layer 2: lane holds h[m=quad*4+reg][n=nb*16+lane15]; d == reg.
    float vals[7];
    #pragma unroll
    for (int k = 0; k < 7; k++) vals[k] = 0.0f;
    #pragma unroll
    for (int nb = 0; nb < 4; nb++) {
      float4 w2r = *(const float4*)(w2s + (nb * 16 + lane15) * 4);
      float hr0 = fmaxf(acc[nb][0] + b1x[nb], 0.0f);
      vals[0] = fmaf(hr0, w2r.x, vals[0]);
      vals[4] = fmaf(hr0, w2r.y, vals[4]);
      vals[5] = fmaf(hr0, w2r.z, vals[5]);
      vals[6] = fmaf(hr0, w2r.w, vals[6]);
      float hr1 = fmaxf(acc[nb][1] + b1x[nb], 0.0f);
      float hr2 = fmaxf(acc[nb][2] + b1x[nb], 0.0f);
      float hr3 = fmaxf(acc[nb][3] + b1x[nb], 0.0f);
      vals[1] = fmaf(hr1, w2r.x, vals[1]);
      vals[2] = fmaf(hr2, w2r.x, vals[2]);
      vals[3] = fmaf(hr3, w2r.x, vals[3]);
    }
    // DPP rotate-reduce over the 16-lane row (pure VALU, no DS/lgkmcnt)
    #pragma unroll
    for (int k = 0; k < 7; k++) {
      DPP_ADD(vals[k], 0x121);  // row_ror:1
      DPP_ADD(vals[k], 0x122);  // row_ror:2
      DPP_ADD(vals[k], 0x124);  // row_ror:4
      DPP_ADD(vals[k], 0x128);  // row_ror:8
    }

    // ---- park: v0 f32 (feeds sigma); diffs+rgb raw sums as f16
    if (lane15 == 0) {
      int sE = sbase + quad;
      rec_v0[sE] = vals[0];
      rec_h[sE][0] = __float2half(vals[1] - vals[0]);
      rec_h[sE][1] = __float2half(vals[2] - vals[0]);
      rec_h[sE][2] = __float2half(vals[3] - vals[0]);
      rec_h[sE][3] = __float2half(vals[4]);
      rec_h[sE][4] = __float2half(vals[5]);
      rec_h[sE][5] = __float2half(vals[6]);
    }
  }

  __syncthreads();

  // ---- composite: per-sample epilogue (96 threads) + shfl scan + shfl reduce
  float b2_0 = b2f[0], b2_1 = b2f[1], b2_2 = b2f[2], b2_3 = b2f[3];
  float a = 0.f, l = 0.f, pcr = 0.f, pcg = 0.f, pcb = 0.f, pnx = 0.f, pny = 0.f, pnz = 0.f, pdt = 0.f;
  if (tid < S_PER) {
    float v0 = rec_v0[tid];
    float d1 = __half2float(rec_h[tid][0]);
    float d2 = __half2float(rec_h[tid][1]);
    float d3 = __half2float(rec_h[tid][2]);
    float v4 = __half2float(rec_h[tid][3]);
    float v5 = __half2float(rec_h[tid][4]);
    float v6 = __half2float(rec_h[tid][5]);
    float sdf0 = v0 + b2_0;
    float g0 = d1 * 100.0f;
    float g1 = d2 * 100.0f;
    float g2 = d3 * 100.0f;
    size_t gid = (size_t)ray * S_PER + tid;
    stout<BF16>(out, (size_t)32768 + gid * 3 + 0, g0);
    stout<BF16>(out, (size_t)32768 + gid * 3 + 1, g1);
    stout<BF16>(out, (size_t)32768 + gid * 3 + 2, g2);
    pcr = 1.0f / (1.0f + expf(-(v4 + b2_1))) * 1.002f - 0.001f;
    pcg = 1.0f / (1.0f + expf(-(v5 + b2_2))) * 1.002f - 0.001f;
    pcb = 1.0f / (1.0f + expf(-(v6 + b2_3))) * 1.002f - 0.001f;
    pdt = tn + span * (((float)tid + 0.5f) * (1.0f / (float)S_PER));
    float ex = ox + pdt * dx, ey = oy + pdt * dy, ez = oz + pdt * dz;
    float pn = sqrtf(ex * ex + ey * ey + ez * ez);
    float shifted = sdf0 + pn - 0.5f;
    float xarg = -shifted * 80.0f;
    float sigma = (xarg > 20.0f) ? xarg : log1pf(expf(xarg));
    a = 1.0f - expf(-sigma * delta);
    float gl = sqrtf(g0 * g0 + g1 * g1 + g2 * g2) + 1e-8f;
    float igl = 1.0f / gl;
    pnx = g0 * igl; pny = g1 * igl; pnz = g2 * igl;
    l = logf(1.0f - a + 1e-10f);
  }

  // inclusive prefix over 96 log-terms: wave-scan + 1-float cross-wave fixup
  float lv = l;   // zero for tid >= 96
  #pragma unroll
  for (int off = 1; off < 64; off <<= 1) {
    float up = __shfl_up(lv, off, 64);
    if (lane >= off) lv += up;
  }
  if (tid == 63) xfer[0] = lv;   // total of samples 0..63
  __syncthreads();
  if (tid >= 64 && tid < S_PER) lv += xfer[0];

  float T = expf(lv - l);        // exclusive prefix -> transmittance
  float w = (tid < S_PER) ? a * T : 0.0f;
  float q[8];
  q[0] = w;
  q[1] = w * pcr; q[2] = w * pcg; q[3] = w * pcb;
  q[4] = w * pnx; q[5] = w * pny; q[6] = w * pnz;
  q[7] = w * pdt;
  #pragma unroll
  for (int off = 1; off < 64; off <<= 1) {
    #pragma unroll
    for (int k = 0; k < 8; k++) q[k] += __shfl_xor(q[k], off, 64);
  }
  if (lane == 0) {
    #pragma unroll
    for (int k = 0; k < 8; k++) red[wave][k] = q[k];
  }
  __syncthreads();
  if (tid == 0) {
    float R[8];
    #pragma unroll
    for (int k = 0; k < 8; k++) R[k] = red[0][k] + red[1][k] + red[2][k] + red[3][k];
    float wsum = R[0];
    float nl = sqrtf(R[4] * R[4] + R[5] * R[5] + R[6] * R[6]) + 1e-8f;
    float inl = 1.0f / nl;
    float nrm3[3] = {R[4], R[5], R[6]};
    float rgb3[3] = {R[1], R[2], R[3]};
    #pragma unroll
    for (int c = 0; c < 3; c++) {
      float n = (nrm3[c] * inl + 1.0f) * 0.5f * wsum;
      stout<BF16>(out, (size_t)(c * 4096 + ray), rgb3[c] + 1.0f - wsum);
      stout<BF16>(out, (size_t)(20480 + c * 4096 + ray), n);
    }
    stout<BF16>(out, (size_t)(12288 + ray), R[7]);
    stout<BF16>(out, (size_t)(16384 + ray), wsum);
  }
}

__global__ __launch_bounds__(256) void fused_kernel(
    const void* __restrict__ ro,
    const void* __restrict__ rd,
    const float* __restrict__ ws,
    void* __restrict__ out) {
  __shared__ __align__(16) unsigned short w1s[15360];  // 30 KB compact
  __shared__ float w2s[256];                           // 1 KB
  __shared__ float rec_v0[S_PER];                      // 384 B
  __shared__ __half rec_h[S_PER][6];                   // 1152 B
  __shared__ float xfer[1];
  __shared__ float red[4][8];
  // ~33.4 KB -> 4 blocks/CU (occupancy is VGPR-binned anyway; see R21 note)

  if (detect_bf16(rd)) fused_body<true >(ro, rd, ws, out, w1s, w2s, rec_v0, rec_h, xfer, red);
  else                 fused_body<false>(ro, rd, ws, out, w1s, w2s, rec_v0, rec_h, xfer, red);
}

extern "C" void kernel_launch(void* const* d_in, const int* in_sizes, int n_in,
                              void* d_out, int out_size, void* d_ws, size_t ws_size,
                              hipStream_t stream) {
  const void* planes = d_in[0];
  const void* ro     = d_in[1];
  const void* rd     = d_in[2];
  const void* W1     = d_in[3];
  const void* b1     = d_in[4];
  const void* W2     = d_in[5];
  const void* b2     = d_in[6];
  float* ws = (float*)d_ws;

  setup_kernel<<<304, 256, 0, stream>>>(planes, W1, b1, W2, b2, rd, ws);
  fused_kernel<<<NUM_RAYS, 256, 0, stream>>>(ro, rd, ws, d_out);
}

// Round 9
// 242.916 us; speedup vs baseline: 1.4123x; 1.4123x over previous
//
#include <hip/hip_runtime.h>
#include <hip/hip_bf16.h>
#include <hip/hip_fp16.h>

#define NUM_RAYS 4096
#define S_PER 96
#define NPTS (NUM_RAYS * S_PER)
#define CCH 80
#define HID 64

// ws layout (byte offsets)
#define WSB_W2     256       // 256 f32 (64x4)
#define WSB_B1     1536      // 64 f32
#define WSB_B2     1856      // 4 f32
#define WSB_W1S    4096      // 15360 f16 shorts, compact MFMA B-frag order (30720 B)
#define WSB_PT     40960     // 983040 f16: planesT [p][y*64+x][80]  (1.97 MB)

// w1s compact layout (shorts): plane p base = p*5120;
//  ccl 0,1: + ccl*2048 + (nb*64+lane)*8 + j        (k = 8*quad+j, ch = ccl*32+k)
//  ccl 2:   + 4096     + (nb*32+(lane&31))*8 + j   (quads 0,1 only; ch = 64+8*quad+j)
//
// LEDGER:
// R17 global B-frags: 232->316 (vmcnt before MFMA + 2x L2). LDS-stage W1.
// R19 launch_bounds(256,4): 64-VGPR cap -> 2.7GB scratch spill. Never cap.
// R20 WIN 232->203: f16 feature path, v_pk_fma_f16 bilinear, f16 MFMA.
// R21 NEUTRAL: LDS 32768 (5 blk/CU possible) but occupancy VGPR-BINNED
//   (waves halve at 64/128/256): VGPR 80 => 4 waves/SIMD regardless of LDS.
// R23 REGRESS 204->290: 9-step tap-prefetch pipeline cost +68 VGPR (148),
//   crossed the 128 bin -> occupancy 11%. SW tap prefetch doesn't fit under
//   the bin; compiler's own schedule at VGPR 80 wins. Pipeline path CLOSED.
// R24: R21 base + DPP rotate-reduce (row_ror 1/2/4/8 v_add_f32) replacing
//   28 ds_swizzle shfl_xor + lgkmcnt chains per iteration. Register-neutral.

// d_out layout (elements of output dtype):
// [0) comp_rgb 3*4096 | [12288) depth 4096 | [16384) opacity 4096
// [20480) comp_normal 3*4096 | [32768) sdf_grad 393216*3

typedef __attribute__((ext_vector_type(8))) _Float16 half8;
typedef __attribute__((ext_vector_type(4))) float f32x4;

__device__ __forceinline__ float bf2f(__hip_bfloat16 v) { return __bfloat162float(v); }

// f32 -> f16 bits (RTN)
__device__ __forceinline__ short f2hs(float f) {
  __half h = __float2half(f);
  short s; __builtin_memcpy(&s, &h, 2); return s;
}

template <bool BF16>
__device__ __forceinline__ float ldin(const void* p, size_t i) {
  if (BF16) return bf2f(((const __hip_bfloat16*)p)[i]);
  else      return ((const float*)p)[i];
}
template <bool BF16>
__device__ __forceinline__ void stout(void* p, size_t i, float v) {
  if (BF16) ((__hip_bfloat16*)p)[i] = __float2bfloat16(v);
  else      ((float*)p)[i] = v;
}

__device__ __forceinline__ __half2 h2cast(unsigned u) {
  __half2 r; __builtin_memcpy(&r, &u, 4); return r;
}

// DPP rotate-add: v += row_ror<N>(v). Pure VALU (no DS op, no lgkmcnt).
// Rotations 1,2,4,8 sum all 16 lanes of each DPP row (= quad group).
#define DPP_ADD(V, CTRL)                                                     \
  do {                                                                       \
    int s_ = __float_as_int(V);                                              \
    int t_ = __builtin_amdgcn_update_dpp(0, s_, (CTRL), 0xF, 0xF, true);     \
    V += __int_as_float(t_);                                                 \
  } while (0)

// Per-wave dtype self-detection: bf16 ray-dir norms ~1; f32-misread is garbage.
__device__ __forceinline__ bool detect_bf16(const void* rdv) {
  int lane = threadIdx.x & 63;
  const __hip_bfloat16* p = (const __hip_bfloat16*)rdv;
  float x = bf2f(p[lane * 3 + 0]);
  float y = bf2f(p[lane * 3 + 1]);
  float z = bf2f(p[lane * 3 + 2]);
  float n2 = x * x + y * y + z * z;
  bool ok = (n2 > 0.95f) && (n2 < 1.05f);
  return __ballot(ok) == ~0ull;
}

template <bool BF16>
__device__ __forceinline__ void prep_body(const void* __restrict__ W1,
                                          const void* __restrict__ b1,
                                          const void* __restrict__ W2,
                                          const void* __restrict__ b2,
                                          float* __restrict__ ws, int tid) {
  unsigned short* w1sw = (unsigned short*)((char*)ws + WSB_W1S);
  if (tid < 15360) {
    int p = tid / 5120;
    int r = tid - p * 5120;
    int ch, n;
    if (r < 4096) {
      int ccl  = r >> 11;
      int r2   = r & 2047;
      int j    = r2 & 7;
      int lane = (r2 >> 3) & 63;
      int nb   = r2 >> 9;
      ch = ccl * 32 + 8 * (lane >> 4) + j;
      n  = nb * 16 + (lane & 15);
    } else {
      int r2   = r - 4096;
      int j    = r2 & 7;
      int l31  = (r2 >> 3) & 31;
      int nb   = r2 >> 8;
      ch = 64 + 8 * (l31 >> 4) + j;
      n  = nb * 16 + (l31 & 15);
    }
    w1sw[tid] = (unsigned short)f2hs(ldin<BF16>(W1, (size_t)(p * 80 + ch) * 64 + n));
  }
  float* w2f = (float*)((char*)ws + WSB_W2);
  float* b1f = (float*)((char*)ws + WSB_B1);
  float* b2f = (float*)((char*)ws + WSB_B2);
  if (tid < 256) w2f[tid] = ldin<BF16>(W2, tid);
  if (tid < 64)  b1f[tid] = ldin<BF16>(b1, tid);
  if (tid < 4)   b2f[tid] = ldin<BF16>(b2, tid);
}

// planes[p][c][y][x] -> planesT[p][y*64+x][80] (f16, channel-last).
template <bool BF16>
__device__ __forceinline__ void transpose_body(const void* __restrict__ planes,
                                               float* __restrict__ ws) {
  int b  = blockIdx.x;
  int tt = b & 15;
  int ct = (b >> 4) % 5;
  int p  = b / 80;
  int tex = tt * 256 + threadIdx.x;
  unsigned u[8];
  #pragma unroll
  for (int i = 0; i < 8; i++) {
    int c0 = ct * 16 + 2 * i;
    float v0 = ldin<BF16>(planes, ((size_t)(p * 80 + c0) * 4096) + tex);
    float v1 = ldin<BF16>(planes, ((size_t)(p * 80 + c0 + 1) * 4096) + tex);
    unsigned s0 = (unsigned short)f2hs(v0);
    unsigned s1 = (unsigned short)f2hs(v1);
    u[i] = s0 | (s1 << 16);
  }
  unsigned short* ptb = (unsigned short*)((char*)ws + WSB_PT);
  uint4* dst = (uint4*)(ptb + ((size_t)(p * 4096 + tex) * 80 + ct * 16));
  dst[0] = make_uint4(u[0], u[1], u[2], u[3]);
  dst[1] = make_uint4(u[4], u[5], u[6], u[7]);
}

// blocks 0..239: plane transpose; blocks 240..303: weight prep
__global__ void setup_kernel(const void* __restrict__ planes,
                             const void* __restrict__ W1,
                             const void* __restrict__ b1,
                             const void* __restrict__ W2,
                             const void* __restrict__ b2,
                             const void* __restrict__ rd,
                             float* __restrict__ ws) {
  bool bf = detect_bf16(rd);
  if (blockIdx.x < 240) {
    if (bf) transpose_body<true >(planes, ws);
    else    transpose_body<false>(planes, ws);
  } else {
    int tid = (blockIdx.x - 240) * 256 + threadIdx.x;
    if (bf) prep_body<true >(W1, b1, W2, b2, ws, tid);
    else    prep_body<false>(W1, b1, W2, b2, ws, tid);
  }
}

struct TapInfo {
  float w00, w10, w01, w11;
  int o00, o10, o01, o11;   // texel indices (y*64+x)
};
__device__ __forceinline__ TapInfo tap_setup(float u, float v) {
  TapInfo t;
  float fx = u * 32.0f + 31.5f;
  float fy = v * 32.0f + 31.5f;
  float flx = floorf(fx), fly = floorf(fy);
  int x0 = (int)flx, y0 = (int)fly;
  float wx = fx - flx, wy = fy - fly;
  int x1 = x0 + 1, y1 = y0 + 1;
  bool vx0 = (x0 >= 0) && (x0 < 64);
  bool vx1 = (x1 >= 0) && (x1 < 64);
  bool vy0 = (y0 >= 0) && (y0 < 64);
  bool vy1 = (y1 >= 0) && (y1 < 64);
  int cx0 = min(max(x0, 0), 63), cx1 = min(max(x1, 0), 63);
  int cy0 = min(max(y0, 0), 63), cy1 = min(max(y1, 0), 63);
  t.w00 = (1.0f - wx) * (1.0f - wy) * ((vx0 && vy0) ? 1.0f : 0.0f);
  t.w10 = wx * (1.0f - wy)          * ((vx1 && vy0) ? 1.0f : 0.0f);
  t.w01 = (1.0f - wx) * wy          * ((vx0 && vy1) ? 1.0f : 0.0f);
  t.w11 = wx * wy                   * ((vx1 && vy1) ? 1.0f : 0.0f);
  t.o00 = cy0 * 64 + cx0; t.o10 = cy0 * 64 + cx1;
  t.o01 = cy1 * 64 + cx0; t.o11 = cy1 * 64 + cx1;
  return t;
}

// Block = 1 ray (256 threads) — R12 shape, the measured optimum:
// scalar-bilinear A-frag build (VALU, f16 packed) + single MFMA chain.
template <bool BF16>
__device__ __forceinline__ void fused_body(const void* __restrict__ ro,
                                           const void* __restrict__ rd,
                                           const float* __restrict__ ws,
                                           void* __restrict__ out,
                                           unsigned short* __restrict__ w1s,
                                           float* __restrict__ rec_v0,
                                           __half (*__restrict__ rec_h)[6],
                                           float* __restrict__ xfer,
                                           float (*__restrict__ red)[8]) {
  const unsigned short* ptb = (const unsigned short*)((const char*)ws + WSB_PT);
  const float* w2f = (const float*)((const char*)ws + WSB_W2);
  const float* b1f = (const float*)((const char*)ws + WSB_B1);
  const float* b2f = (const float*)((const char*)ws + WSB_B2);

  int tid = threadIdx.x;
  int wave = tid >> 6;
  int lane = tid & 63;
  int lane15 = lane & 15;
  int quad = lane >> 4;
  int ray = blockIdx.x;

  // stage compact W1 (1920 uint4) into LDS
  {
    const uint4* src = (const uint4*)((const char*)ws + WSB_W1S);
    uint4* dst = (uint4*)w1s;
    #pragma unroll
    for (int t = 0; t < 8; t++) {
      int idx = tid + 256 * t;
      if (idx < 1920) dst[idx] = src[idx];
    }
  }
  // W2 rows this lane needs: 16 VGPRs (replaces the old w2s LDS buffer)
  float4 w2reg[4];
  #pragma unroll
  for (int nb = 0; nb < 4; nb++)
    w2reg[nb] = *(const float4*)(w2f + (nb * 16 + lane15) * 4);

  // ray data (uniform across block)
  float ox = ldin<BF16>(ro, (size_t)ray*3+0), oy = ldin<BF16>(ro, (size_t)ray*3+1), oz = ldin<BF16>(ro, (size_t)ray*3+2);
  float dx = ldin<BF16>(rd, (size_t)ray*3+0), dy = ldin<BF16>(rd, (size_t)ray*3+1), dz = ldin<BF16>(rd, (size_t)ray*3+2);
  float o3[3] = {ox, oy, oz}, d3[3] = {dx, dy, dz};
  float tmin = -1e30f, tmax = 1e30f;
  #pragma unroll
  for (int k = 0; k < 3; k++) {
    float sd = (fabsf(d3[k]) < 1e-9f) ? 1e-9f : d3[k];
    float ta = (-0.6f - o3[k]) / sd;
    float tb = ( 0.6f - o3[k]) / sd;
    tmin = fmaxf(tmin, fminf(ta, tb));
    tmax = fminf(tmax, fmaxf(ta, tb));
  }
  float tn = fmaxf(tmin, 0.0f);
  float span = fmaxf(tmax - tn, 0.0f);
  float delta = span * (1.0f / (float)S_PER);
  // per-lane b1 (4 VGPRs)
  float b1x[4];
  #pragma unroll
  for (int nb = 0; nb < 4; nb++) b1x[nb] = b1f[nb * 16 + lane15];

  __syncthreads();

  #pragma unroll 1
  for (int it = 0; it < 6; it++) {
    int sbase = it * 16 + wave * 4;

    // ---- feature stage: lane feeds A-row m = lane15 (sample sF, decode d)
    int sF = sbase + (lane15 >> 2);
    int d  = lane15 & 3;
    float depF = tn + span * (((float)sF + 0.5f) * (1.0f / (float)S_PER));
    float px = ox + depF * dx, py = oy + depF * dy, pz = oz + depF * dz;
    if (d == 1) px += 0.01f;
    if (d == 2) py += 0.01f;
    if (d == 3) pz += 0.01f;
    if (d > 0) {
      px = fminf(fmaxf(px, -0.6f), 0.6f);
      py = fminf(fmaxf(py, -0.6f), 0.6f);
      pz = fminf(fmaxf(pz, -0.6f), 0.6f);
    }
    const float inv = 1.0f / 0.6f;
    float ux = px * inv, uy = py * inv, uz = pz * inv;

    f32x4 acc[4];
    #pragma unroll
    for (int nb = 0; nb < 4; nb++) acc[nb] = (f32x4){0.f, 0.f, 0.f, 0.f};

    #pragma unroll 1
    for (int p = 0; p < 3; p++) {
      float u = (p == 2) ? uy : ux;
      float v = (p == 0) ? uy : uz;
      TapInfo t = tap_setup(u, v);
      // f16 broadcast weights (one cvt+pack each, once per plane)
      __half2 hw00 = __float2half2_rn(t.w00);
      __half2 hw10 = __float2half2_rn(t.w10);
      __half2 hw01 = __float2half2_rn(t.w01);
      __half2 hw11 = __float2half2_rn(t.w11);
      // hoisted per-plane corner pointers incl. this lane's k-offset (8*quad ch)
      const unsigned short* c00p = ptb + (size_t)p * 327680 + t.o00 * 80 + 8 * quad;
      const unsigned short* c10p = ptb + (size_t)p * 327680 + t.o10 * 80 + 8 * quad;
      const unsigned short* c01p = ptb + (size_t)p * 327680 + t.o01 * 80 + 8 * quad;
      const unsigned short* c11p = ptb + (size_t)p * 327680 + t.o11 * 80 + 8 * quad;
      const unsigned short* w1p = w1s + p * 5120;
      #pragma unroll
      for (int ccl = 0; ccl < 3; ccl++) {
        int4 afi = {0, 0, 0, 0};
        if (ccl < 2 || quad < 2) {   // live lanes (ccl2 quads 2,3 are pad-K)
          uint4 q00 = *(const uint4*)(c00p + 32 * ccl);
          uint4 q10 = *(const uint4*)(c10p + 32 * ccl);
          uint4 q01 = *(const uint4*)(c01p + 32 * ccl);
          uint4 q11 = *(const uint4*)(c11p + 32 * ccl);
          unsigned u00[4] = {q00.x, q00.y, q00.z, q00.w};
          unsigned u10[4] = {q10.x, q10.y, q10.z, q10.w};
          unsigned u01[4] = {q01.x, q01.y, q01.z, q01.w};
          unsigned u11[4] = {q11.x, q11.y, q11.z, q11.w};
          int ae[4];
          #pragma unroll
          for (int q = 0; q < 4; q++) {
            // packed f16 bilinear: 1 v_pk_mul_f16 + 3 v_pk_fma_f16
            __half2 f = __hmul2(h2cast(u00[q]), hw00);
            f = __hfma2(h2cast(u10[q]), hw10, f);
            f = __hfma2(h2cast(u01[q]), hw01, f);
            f = __hfma2(h2cast(u11[q]), hw11, f);
            int fi; __builtin_memcpy(&fi, &f, 4);
            ae[q] = fi;
          }
          afi.x = ae[0]; afi.y = ae[1]; afi.z = ae[2]; afi.w = ae[3];
        }
        half8 afr;
        __builtin_memcpy(&afr, &afi, 16);
        #pragma unroll
        for (int nb = 0; nb < 4; nb++) {
          // compact B-frag: ccl 0,1 full; ccl 2 half (quads 2,3 alias — A is 0)
          int boff = (ccl < 2) ? (ccl * 2048 + (nb * 64 + lane) * 8)
                               : (4096 + (nb * 32 + (lane & 31)) * 8);
          half8 bfr = *(const half8*)(w1p + boff);
          acc[nb] = __builtin_amdgcn_mfma_f32_16x16x32_f16(afr, bfr, acc[nb], 0, 0, 0);
        }
      }
    }

    // ---- layer 2: lane holds h[m=quad*4+reg][n=nb*16+lane15]; d == reg.
    float vals[7];
    #pragma unroll
    for (int k = 0; k < 7; k++) vals[k] = 0.0f;
    #pragma unroll
    for (int nb = 0; nb < 4; nb++) {
      float4 w2r = w2reg[nb];
      float hr0 = fmaxf(acc[nb][0] + b1x[nb], 0.0f);
      vals[0] = fmaf(hr0, w2r.x, vals[0]);
      vals[4] = fmaf(hr0, w2r.y, vals[4]);
      vals[5] = fmaf(hr0, w2r.z, vals[5]);
      vals[6] = fmaf(hr0, w2r.w, vals[6]);
      float hr1 = fmaxf(acc[nb][1] + b1x[nb], 0.0f);
      float hr2 = fmaxf(acc[nb][2] + b1x[nb], 0.0f);
      float hr3 = fmaxf(acc[nb][3] + b1x[nb], 0.0f);
      vals[1] = fmaf(hr1, w2r.x, vals[1]);
      vals[2] = fmaf(hr2, w2r.x, vals[2]);
      vals[3] = fmaf(hr3, w2r.x, vals[3]);
    }
    // DPP rotate-reduce over each 16-lane row (= quad group); pure VALU,
    // replaces 28 ds_swizzle shfl_xor + serial lgkmcnt waits.
    #pragma unroll
    for (int k = 0; k < 7; k++) {
      DPP_ADD(vals[k], 0x121);  // row_ror:1
      DPP_ADD(vals[k], 0x122);  // row_ror:2
      DPP_ADD(vals[k], 0x124);  // row_ror:4
      DPP_ADD(vals[k], 0x128);  // row_ror:8
    }

    // ---- park: v0 f32 (feeds sigma); diffs+rgb raw sums as f16
    if (lane15 == 0) {
      int sE = sbase + quad;
      rec_v0[sE] = vals[0];
      rec_h[sE][0] = __float2half(vals[1] - vals[0]);
      rec_h[sE][1] = __float2half(vals[2] - vals[0]);
      rec_h[sE][2] = __float2half(vals[3] - vals[0]);
      rec_h[sE][3] = __float2half(vals[4]);
      rec_h[sE][4] = __float2half(vals[5]);
      rec_h[sE][5] = __float2half(vals[6]);
    }
  }

  __syncthreads();

  // ---- composite: per-sample epilogue (96 threads) + shfl scan + shfl reduce
  float b2_0 = b2f[0], b2_1 = b2f[1], b2_2 = b2f[2], b2_3 = b2f[3];
  float a = 0.f, l = 0.f, pcr = 0.f, pcg = 0.f, pcb = 0.f, pnx = 0.f, pny = 0.f, pnz = 0.f, pdt = 0.f;
  if (tid < S_PER) {
    float v0 = rec_v0[tid];
    float d1 = __half2float(rec_h[tid][0]);
    float d2 = __half2float(rec_h[tid][1]);
    float d3 = __half2float(rec_h[tid][2]);
    float v4 = __half2float(rec_h[tid][3]);
    float v5 = __half2float(rec_h[tid][4]);
    float v6 = __half2float(rec_h[tid][5]);
    float sdf0 = v0 + b2_0;
    float g0 = d1 * 100.0f;
    float g1 = d2 * 100.0f;
    float g2 = d3 * 100.0f;
    size_t gid = (size_t)ray * S_PER + tid;
    stout<BF16>(out, (size_t)32768 + gid * 3 + 0, g0);
    stout<BF16>(out, (size_t)32768 + gid * 3 + 1, g1);
    stout<BF16>(out, (size_t)32768 + gid * 3 + 2, g2);
    pcr = 1.0f / (1.0f + expf(-(v4 + b2_1))) * 1.002f - 0.001f;
    pcg = 1.0f / (1.0f + expf(-(v5 + b2_2))) * 1.002f - 0.001f;
    pcb = 1.0f / (1.0f + expf(-(v6 + b2_3))) * 1.002f - 0.001f;
    pdt = tn + span * (((float)tid + 0.5f) * (1.0f / (float)S_PER));
    float ex = ox + pdt * dx, ey = oy + pdt * dy, ez = oz + pdt * dz;
    float pn = sqrtf(ex * ex + ey * ey + ez * ez);
    float shifted = sdf0 + pn - 0.5f;
    float xarg = -shifted * 80.0f;
    float sigma = (xarg > 20.0f) ? xarg : log1pf(expf(xarg));
    a = 1.0f - expf(-sigma * delta);
    float gl = sqrtf(g0 * g0 + g1 * g1 + g2 * g2) + 1e-8f;
    float igl = 1.0f / gl;
    pnx = g0 * igl; pny = g1 * igl; pnz = g2 * igl;
    l = logf(1.0f - a + 1e-10f);
  }

  // inclusive prefix over 96 log-terms: wave-scan + 1-float cross-wave fixup
  float lv = l;   // zero for tid >= 96
  #pragma unroll
  for (int off = 1; off < 64; off <<= 1) {
    float up = __shfl_up(lv, off, 64);
    if (lane >= off) lv += up;
  }
  if (tid == 63) xfer[0] = lv;   // total of samples 0..63
  __syncthreads();
  if (tid >= 64 && tid < S_PER) lv += xfer[0];

  float T = expf(lv - l);        // exclusive prefix -> transmittance
  float w = (tid < S_PER) ? a * T : 0.0f;
  float q[8];
  q[0] = w;
  q[1] = w * pcr; q[2] = w * pcg; q[3] = w * pcb;
  q[4] = w * pnx; q[5] = w * pny; q[6] = w * pnz;
  q[7] = w * pdt;
  #pragma unroll
  for (int off = 1; off < 64; off <<= 1) {
    #pragma unroll
    for (int k = 0; k < 8; k++) q[k] += __shfl_xor(q[k], off, 64);
  }
  if (lane == 0) {
    #pragma unroll
    for (int k = 0; k < 8; k++) red[wave][k] = q[k];
  }
  __syncthreads();
  if (tid == 0) {
    float R[8];
    #pragma unroll
    for (int k = 0; k < 8; k++) R[k] = red[0][k] + red[1][k] + red[2][k] + red[3][k];
    float wsum = R[0];
    float nl = sqrtf(R[4] * R[4] + R[5] * R[5] + R[6] * R[6]) + 1e-8f;
    float inl = 1.0f / nl;
    float nrm3[3] = {R[4], R[5], R[6]};
    float rgb3[3] = {R[1], R[2], R[3]};
    #pragma unroll
    for (int c = 0; c < 3; c++) {
      float n = (nrm3[c] * inl + 1.0f) * 0.5f * wsum;
      stout<BF16>(out, (size_t)(c * 4096 + ray), rgb3[c] + 1.0f - wsum);
      stout<BF16>(out, (size_t)(20480 + c * 4096 + ray), n);
    }
    stout<BF16>(out, (size_t)(12288 + ray), R[7]);
    stout<BF16>(out, (size_t)(16384 + ray), wsum);
  }
}

__global__ __launch_bounds__(256) void fused_kernel(
    const void* __restrict__ ro,
    const void* __restrict__ rd,
    const float* __restrict__ ws,
    void* __restrict__ out) {
  __shared__ __align__(16) unsigned short w1s[15360];  // 30 KB compact
  __shared__ float rec_v0[S_PER];                      // 384 B
  __shared__ __half rec_h[S_PER][6];                   // 1152 B
  __shared__ float xfer[1];
  __shared__ float red[4][8];
  // 32768 B total

  if (detect_bf16(rd)) fused_body<true >(ro, rd, ws, out, w1s, rec_v0, rec_h, xfer, red);
  else                 fused_body<false>(ro, rd, ws, out, w1s, rec_v0, rec_h, xfer, red);
}

extern "C" void kernel_launch(void* const* d_in, const int* in_sizes, int n_in,
                              void* d_out, int out_size, void* d_ws, size_t ws_size,
                              hipStream_t stream) {
  const void* planes = d_in[0];
  const void* ro     = d_in[1];
  const void* rd     = d_in[2];
  const void* W1     = d_in[3];
  const void* b1     = d_in[4];
  const void* W2     = d_in[5];
  const void* b2     = d_in[6];
  float* ws = (float*)d_ws;

  setup_kernel<<<304, 256, 0, stream>>>(planes, W1, b1, W2, b2, rd, ws);
  fused_kernel<<<NUM_RAYS, 256, 0, stream>>>(ro, rd, ws, d_out);
}